// Round 3
// baseline (501.417 us; speedup 1.0000x reference)
//
#include <hip/hip_runtime.h>

// ---------------------------------------------------------------------------
// SLMGAE edge scorer, round 6.
//   P = zc @ fc1_w[0:400] + b1,  Q = zc @ fc1_w[400:800]   (per node)
//   per edge: h1 = relu(P[s]+Q[d]); h2 = relu(h1@W2+b2); h3 = relu(h2@W3+b3);
//   out = h3@w4 + b4
// Round-6 changes vs round 5 (R5 proved occupancy is NOT the limiter:
// +46% occupancy -> -2% time. Remaining cost scales with per-edge work:
// LDS reads ~71us/CU, weight staging 950 MB, barriers):
//   * edge_kernel block 256 -> 512 threads (8 waves, 256 edges/block):
//     weight-staging traffic and per-edge barrier count HALVE; same 53.2 KB
//     LDS dbuf now amortized over 2x edges; per-wave code unchanged (84 VGPR).
//     __launch_bounds__(512,4): VGPR cap 128, 2 blocks/CU (16 waves/CU).
//   * fc3 k-blocks 14 -> 13: kb3=13 covers k=208..223 which is all-zero
//     weight (real k stops at 201) -- exact skip of 4 MFMAs + 4 ds_reads +
//     1 stage load per wave.
// ---------------------------------------------------------------------------

using u16    = unsigned short;
using bf16x8 = __attribute__((ext_vector_type(8))) short;   // 8 bf16 (4 VGPR)
using f32x4  = __attribute__((ext_vector_type(4))) float;
using f32x16 = __attribute__((ext_vector_type(16))) float;
using i32x4  = __attribute__((ext_vector_type(4))) int;

#define NN   20000   // nodes
#define NNP  20032   // nodes padded (multiple of 64)
#define KD   416     // 400 padded to multiple of 32 (col 400 = bias-one)
#define NE   500000  // edges

// fragment-order element counts
#define W1F_ELEMS (50*13*512)    // 50 n-tiles(16) x 13 kb(32) x 64 lanes x 8
#define W2F_ELEMS (7*26*512)     // 7 n-tiles(32) x 26 kb(16) x 64 x 8
#define W3F_ELEMS (4*14*512)     // 4 n-tiles(32) x 14 kb(16) x 64 x 8
#define F4_ELEMS  128
#define PREP_TOT  (W1F_ELEMS + W2F_ELEMS + W3F_ELEMS + F4_ELEMS)

#define ZC_BLOCKS   (NNP / 4)                    // 5008
#define PREP_BLOCKS ((PREP_TOT + 255) / 256)     // 1777

__device__ __forceinline__ u16 f2bf(float f) {              // RNE f32->bf16
  unsigned u = __float_as_uint(f);
  u += 0x7fffu + ((u >> 16) & 1u);
  return (u16)(u >> 16);
}

// pack two f32 -> packed bf16 pair (lo in [15:0]), single HW instr, RNE
__device__ __forceinline__ int cvt_pk_bf16(float lo, float hi) {
  int r;
  asm("v_cvt_pk_bf16_f32 %0, %1, %2" : "=v"(r) : "v"(lo), "v"(hi));
  return r;
}

// async global->LDS 16B: lane l's 16B land at ldsbase + l*16 (linear order)
__device__ __forceinline__ void gl_lds16(const u16* g, u16* l) {
  __builtin_amdgcn_global_load_lds(
      (const __attribute__((address_space(1))) unsigned int*)g,
      (__attribute__((address_space(3))) unsigned int*)l, 16, 0, 0);
}

// ---------------------------------------------------------------------------
// K0 (fused): block role by blockIdx.x
//   [0, ZC_BLOCKS)                : build_zc — per-node tiny MLP + zc_bf rows
//   [ZC_BLOCKS, ZC_BLOCKS+PREP)   : prep_w  — weight transpose/pad/bf16, FRAG
//
// prep_w fragment orders:
//  W1f[g][kb][l][j] = W1t[n=g*16+(l&15)][k=kb*32+(l>>4)*8+j]   (16x16x32 B-frag)
//    W1t[n][k]: k<400 -> fc1 halves; k==400 -> fc1b[n] (n<400); else 0
//  W2f[nt][kb][l][j] = W2t[n=nt*32+(l&31)][k=kb*16+(l>>5)*8+j] (32x32x16 A-frag)
//    W2t[n][k]: n<200: k<400 -> fc2_w[k][n]; k==400 -> fc2b[n]; else 0
//  W3f[nt][kb][l][j] = W3t[n=nt*32+(l&31)][k=kb*16+(l>>5)*8+j]
//    W3t[n][k]: n<100: k<200 -> fc3_w[k][n]; k==200 -> fc3b[n]; else 0
//
// build_zc: zc = [z(64) | m(16) | esm(320) | 1.0 at k=400 | zeros]
// ---------------------------------------------------------------------------
__global__ __launch_bounds__(256) void prep_fused(
    const float* __restrict__ z, const float* __restrict__ cell,
    const float* __restrict__ esm,
    const float* __restrict__ w1, const float* __restrict__ b1,
    const float* __restrict__ w2, const float* __restrict__ b2,
    const float* __restrict__ w3, const float* __restrict__ b3,
    u16* __restrict__ zc,
    const float* __restrict__ fc1, const float* __restrict__ fc1b,
    const float* __restrict__ fc2, const float* __restrict__ fc2b,
    const float* __restrict__ fc3, const float* __restrict__ fc3b,
    const float* __restrict__ fc4,
    u16* __restrict__ W1f, u16* __restrict__ W2f, u16* __restrict__ W3f,
    float* __restrict__ fc4wp)
{
  __shared__ float h1s[4][64];
  __shared__ float h2s[4][32];
  __shared__ float ms[4][16];

  if (blockIdx.x < ZC_BLOCKS) {
    // ------------------------- build_zc ------------------------------------
    int tid = threadIdx.x, g = tid >> 6, t = tid & 63;
    int i = blockIdx.x * 4 + g;
    bool real = (i < NN);
    float c0 = 0, c1 = 0, c2 = 0, c3 = 0;
    if (real) {
      c0 = cell[(size_t)i * 4 + 0]; c1 = cell[(size_t)i * 4 + 1];
      c2 = cell[(size_t)i * 4 + 2]; c3 = cell[(size_t)i * 4 + 3];
    }
    float h = b1[t] + c0 * w1[t] + c1 * w1[64 + t] + c2 * w1[128 + t] + c3 * w1[192 + t];
    h1s[g][t] = fmaxf(h, 0.f);
    __syncthreads();
    if (t < 32) {
      float acc = b2[t];
      #pragma unroll 8
      for (int j = 0; j < 64; j++) acc += h1s[g][j] * w2[j * 32 + t];
      h2s[g][t] = fmaxf(acc, 0.f);
    }
    __syncthreads();
    if (t < 16) {
      float acc = b3[t];
      #pragma unroll 8
      for (int j = 0; j < 32; j++) acc += h2s[g][j] * w3[j * 16 + t];
      ms[g][t] = acc;
    }
    __syncthreads();
    u16* row = zc + (size_t)i * KD;
    for (int k = t; k < KD; k += 64) {
      float v = 0.f;
      if (real) {
        if (k < 64)       v = z[(size_t)i * 64 + k];
        else if (k < 80)  v = ms[g][k - 64];
        else if (k < 400) v = esm[(size_t)i * 320 + (k - 80)];
        else if (k == 400) v = 1.0f;   // bias-one column (fc1b lives in W1f)
      }
      row[k] = f2bf(v);
    }
    return;
  }

  // --------------------------- prep_w --------------------------------------
  int idx = (blockIdx.x - ZC_BLOCKS) * 256 + threadIdx.x;
  if (idx < W1F_ELEMS) {
    int j = idx & 7, l = (idx >> 3) & 63, t = idx >> 9;
    int kb = t % 13, g = t / 13;
    int n = g * 16 + (l & 15);
    int k = kb * 32 + (l >> 4) * 8 + j;
    float v = 0.f;
    if (k < 400) v = (n < 400) ? fc1[(size_t)k * 400 + n]
                               : fc1[(size_t)(400 + k) * 400 + (n - 400)];
    else if (k == 400 && n < 400) v = fc1b[n];
    W1f[idx] = f2bf(v);
  } else if (idx < W1F_ELEMS + W2F_ELEMS) {
    int r = idx - W1F_ELEMS;
    int j = r & 7, l = (r >> 3) & 63, t = r >> 9;
    int kb = t % 26, nt = t / 26;
    int n = nt * 32 + (l & 31);
    int k = kb * 16 + (l >> 5) * 8 + j;
    float v = 0.f;
    if (n < 200) {
      if (k < 400) v = fc2[(size_t)k * 200 + n];
      else if (k == 400) v = fc2b[n];
    }
    W2f[r] = f2bf(v);
  } else if (idx < W1F_ELEMS + W2F_ELEMS + W3F_ELEMS) {
    int r = idx - (W1F_ELEMS + W2F_ELEMS);
    int j = r & 7, l = (r >> 3) & 63, t = r >> 9;
    int kb = t % 14, nt = t / 14;
    int n = nt * 32 + (l & 31);
    int k = kb * 16 + (l >> 5) * 8 + j;
    float v = 0.f;
    if (n < 100) {
      if (k < 200) v = fc3[(size_t)k * 100 + n];
      else if (k == 200) v = fc3b[n];
    }
    W3f[r] = f2bf(v);
  } else if (idx < PREP_TOT) {
    int r = idx - (W1F_ELEMS + W2F_ELEMS + W3F_ELEMS);
    fc4wp[r] = (r < 100) ? fc4[r] : 0.f;
  }
}

// ---------------------------------------------------------------------------
// K2: PQ[NNP][800] = zc_bf @ W1^T (bias via k=400 col), bf16 out.
// Dual 16-row A-tiles per wave; B streamed from frag-ordered W1f (coalesced).
// grid (157, 5): 785 blocks (~3 blocks/CU).  B slab per y = 133 KB, L2-hot.
// ---------------------------------------------------------------------------
__global__ __launch_bounds__(256) void node_gemm(
    const u16* __restrict__ zc, const u16* __restrict__ W1f,
    u16* __restrict__ PQ)
{
  int tid = threadIdx.x, w = tid >> 6, l = tid & 63, lm = l & 15, quad = l >> 4;
  int mbase = blockIdx.x * 128 + w * 32;

  int ra = mbase + lm;       if (ra > NNP - 1) ra = NNP - 1;
  int rb = mbase + 16 + lm;  if (rb > NNP - 1) rb = NNP - 1;
  bf16x8 a0[13], a1[13];
  const u16* arow0 = zc + (size_t)ra * KD + quad * 8;
  const u16* arow1 = zc + (size_t)rb * KD + quad * 8;
  #pragma unroll
  for (int kb = 0; kb < 13; kb++) {
    a0[kb] = *(const bf16x8*)(arow0 + kb * 32);
    a1[kb] = *(const bf16x8*)(arow1 + kb * 32);
  }

  for (int nt = 0; nt < 10; nt++) {
    int g = blockIdx.y * 10 + nt;          // global 16-col tile of the 800
    int ncol = g * 16 + lm;
    const u16* bbase = W1f + ((size_t)g * 13 * 64 + l) * 8;
    f32x4 acc0 = {0.f, 0.f, 0.f, 0.f};
    f32x4 acc1 = {0.f, 0.f, 0.f, 0.f};
    #pragma unroll
    for (int kb = 0; kb < 13; kb++) {
      bf16x8 b = *(const bf16x8*)(bbase + (size_t)kb * 512);
      acc0 = __builtin_amdgcn_mfma_f32_16x16x32_bf16(a0[kb], b, acc0, 0, 0, 0);
      acc1 = __builtin_amdgcn_mfma_f32_16x16x32_bf16(a1[kb], b, acc1, 0, 0, 0);
    }
    #pragma unroll
    for (int r = 0; r < 4; r++) {
      int row0 = mbase + quad * 4 + r;
      int row1 = row0 + 16;
      if (row0 < NNP) PQ[(size_t)row0 * 800 + ncol] = f2bf(acc0[r]);
      if (row1 < NNP) PQ[(size_t)row1 * 800 + ncol] = f2bf(acc1[r]);
    }
  }
}

// ---------------------------------------------------------------------------
// K3: edge kernel — 8 waves x 32 edges = 256 edges/block, mfma 32x32x16,
// weights double-buffered in LDS via async global_load_lds.  Per-tile:
//   issue stage(t+1 -> buf^1)  ||  ds_read+MFMA tile t from buf  ->  sync
// Block=512 halves weight-staging traffic & per-edge barrier count vs 256.
// ---------------------------------------------------------------------------
__global__ __launch_bounds__(512, 4) void edge_kernel(
    const u16* __restrict__ PQ, const u16* __restrict__ W2f,
    const u16* __restrict__ W3f, const float* __restrict__ fc4wp,
    const float* __restrict__ fc4b,
    const int* __restrict__ ei, float* __restrict__ out)
{
  __shared__ __align__(16) u16 wsm[2][26 * 512];   // 2 x 26.6 KB = 53.2 KB

  int tid = threadIdx.x, w = tid >> 6, l = tid & 63;
  int c = l & 31, h = l >> 5;
  int e = blockIdx.x * 256 + w * 32 + c;
  int ec = e < NE ? e : NE - 1;
  int s = ei[ec], d = ei[NE + ec];
  const u16* prow = PQ + (size_t)s * 800 + h * 8;        // P (pre-biased)
  const u16* qrow = PQ + (size_t)d * 800 + 400 + h * 8;  // Q

  // issue fc2 tile-0 stage immediately: L2 latency hides under the gather
  for (int kb = w; kb < 26; kb += 8)
    gl_lds16(W2f + ((size_t)kb * 64 + l) * 8, &wsm[0][kb * 512]);

  // ---- gather -> h1 B-frags (kb 0..24 real; kb 25 = bias-one) -------------
  i32x4 h1i[25];
  #pragma unroll
  for (int kb = 0; kb < 25; kb++) {
    i32x4 pv = *(const i32x4*)(prow + kb * 16);
    i32x4 qv = *(const i32x4*)(qrow + kb * 16);
    i32x4 r;
    #pragma unroll
    for (int j2 = 0; j2 < 4; j2++) {
      unsigned pu = (unsigned)pv[j2], qu = (unsigned)qv[j2];
      float lo = __uint_as_float(pu << 16) + __uint_as_float(qu << 16);
      float hi = __uint_as_float(pu & 0xFFFF0000u) + __uint_as_float(qu & 0xFFFF0000u);
      r[j2] = cvt_pk_bf16(fmaxf(lo, 0.f), fmaxf(hi, 0.f));
    }
    h1i[kb] = r;
  }
  i32x4 bias1 = {0, 0, 0, 0};
  if (h == 0) bias1[0] = 0x3f80;   // h1[k=400] = 1.0 (bf16) for every edge

  __syncthreads();                 // drains vmcnt -> buf0 staged for all waves

  // ---- fc2: 7 ntiles of 32 neurons; dbuf-staged weights; h2 packed --------
  int p2[7][8];
  #pragma unroll
  for (int nt = 0; nt < 7; nt++) {
    int cur = nt & 1;
    if (nt < 6) {                               // prefetch next fc2 tile
      for (int kb = w; kb < 26; kb += 8)
        gl_lds16(W2f + (((size_t)(nt + 1) * 26 + kb) * 64 + l) * 8,
                 &wsm[cur ^ 1][kb * 512]);
    } else {                                    // prefetch fc3 tile 0 (13 kb)
      for (int kb = w; kb < 13; kb += 8)
        gl_lds16(W3f + ((size_t)kb * 64 + l) * 8, &wsm[cur ^ 1][kb * 512]);
    }
    f32x16 acc = {0.f,0.f,0.f,0.f,0.f,0.f,0.f,0.f,0.f,0.f,0.f,0.f,0.f,0.f,0.f,0.f};
    __builtin_amdgcn_s_setprio(1);
    #pragma unroll
    for (int kb = 0; kb < 25; kb++) {
      bf16x8 a = *(const bf16x8*)&wsm[cur][kb * 512 + l * 8];
      acc = __builtin_amdgcn_mfma_f32_32x32x16_bf16(
          a, __builtin_bit_cast(bf16x8, h1i[kb]), acc, 0, 0, 0);
    }
    {  // kb = 25: bias column k=400
      bf16x8 a = *(const bf16x8*)&wsm[cur][25 * 512 + l * 8];
      acc = __builtin_amdgcn_mfma_f32_32x32x16_bf16(
          a, __builtin_bit_cast(bf16x8, bias1), acc, 0, 0, 0);
    }
    __builtin_amdgcn_s_setprio(0);
    #pragma unroll
    for (int q = 0; q < 8; q++)    // relu + pack regs (2q, 2q+1)
      p2[nt][q] = cvt_pk_bf16(fmaxf(acc[2 * q], 0.f), fmaxf(acc[2 * q + 1], 0.f));
    __syncthreads();               // next buf staged AND cur free for reuse
  }

  // ---- transpose: C-layout h2 -> fc3 B-frags via shfl_xor(32) -------------
  // only 13 k-blocks needed: k2 = 208..223 (kb3=13) is all-zero weight
  i32x4 b2f[13];
  #pragma unroll
  for (int kb3 = 0; kb3 < 13; kb3++) {
    int nt = kb3 >> 1;
    i32x4 f;
    #pragma unroll
    for (int jj = 0; jj < 4; jj++) {
      int q0 = (jj & 1) + 4 * (kb3 & 1);
      if (jj < 2) {        // source lives in lower half (h_s = 0)
        int x = __shfl_xor(p2[nt][q0 + 2], 32);
        f[jj] = h ? x : p2[nt][q0];
      } else {             // source lives in upper half (h_s = 1)
        int y = __shfl_xor(p2[nt][q0], 32);
        f[jj] = h ? p2[nt][q0 + 2] : y;
      }
    }
    if (kb3 == 12 && h) f[0] |= 0x3f80;   // h2[k2=200] = 1.0 (fc3 bias-one)
    b2f[kb3] = f;
  }

  // ---- fc3 + fc4 (fc3 tile 0 already staged during fc2 nt=6) --------------
  float osum = 0.f;
  #pragma unroll
  for (int nt3 = 0; nt3 < 4; nt3++) {
    int cur = (7 + nt3) & 1;
    if (nt3 < 3) {                              // prefetch next fc3 tile
      for (int kb = w; kb < 13; kb += 8)
        gl_lds16(W3f + (((size_t)(nt3 + 1) * 14 + kb) * 64 + l) * 8,
                 &wsm[cur ^ 1][kb * 512]);
    }
    f32x16 acc = {0.f,0.f,0.f,0.f,0.f,0.f,0.f,0.f,0.f,0.f,0.f,0.f,0.f,0.f,0.f,0.f};
    __builtin_amdgcn_s_setprio(1);
    #pragma unroll
    for (int kb3 = 0; kb3 < 13; kb3++) {
      bf16x8 a = *(const bf16x8*)&wsm[cur][kb3 * 512 + l * 8];
      acc = __builtin_amdgcn_mfma_f32_32x32x16_bf16(
          a, __builtin_bit_cast(bf16x8, b2f[kb3]), acc, 0, 0, 0);
    }
    __builtin_amdgcn_s_setprio(0);
    #pragma unroll
    for (int r = 0; r < 16; r++) {
      int rho = (r & 3) + 8 * (r >> 2) + 4 * h + 32 * nt3;
      osum += fmaxf(acc[r], 0.f) * fc4wp[rho];   // pad rows: 0 * 0
    }
    if (nt3 < 3) __syncthreads();
  }
  osum += __shfl_xor(osum, 32);     // combine the two k-halves of this edge
  if (h == 0 && e < NE) out[e] = osum + fc4b[0];
}

// ---------------------------------------------------------------------------
extern "C" void kernel_launch(void* const* d_in, const int* in_sizes, int n_in,
                              void* d_out, int out_size, void* d_ws, size_t ws_size,
                              hipStream_t stream) {
  (void)in_sizes; (void)n_in; (void)out_size; (void)ws_size;
  const float* z    = (const float*)d_in[0];
  const int*   ei   = (const int*)d_in[1];
  const float* cell = (const float*)d_in[2];
  const float* esm  = (const float*)d_in[3];
  const float* w1   = (const float*)d_in[4];
  const float* b1   = (const float*)d_in[5];
  const float* w2   = (const float*)d_in[6];
  const float* b2   = (const float*)d_in[7];
  const float* w3   = (const float*)d_in[8];
  const float* b3   = (const float*)d_in[9];
  const float* fc1w = (const float*)d_in[10];
  const float* fc1b = (const float*)d_in[11];
  const float* fc2w = (const float*)d_in[12];
  const float* fc2b = (const float*)d_in[13];
  const float* fc3w = (const float*)d_in[14];
  const float* fc3b = (const float*)d_in[15];
  const float* fc4w = (const float*)d_in[16];
  const float* fc4b = (const float*)d_in[17];
  float* out = (float*)d_out;

  // workspace layout (u16 units, all 16B-aligned): ~49.6 MB
  u16* zc  = (u16*)d_ws;                        // NNP*416
  u16* PQ  = zc  + (size_t)NNP * KD;            // NNP*800
  u16* W1f = PQ  + (size_t)NNP * 800;           // 332800
  u16* W2f = W1f + W1F_ELEMS;                   // 93184
  u16* W3f = W2f + W2F_ELEMS;                   // 28672
  float* fc4wp = (float*)(W3f + W3F_ELEMS);     // 128 f32

  prep_fused<<<ZC_BLOCKS + PREP_BLOCKS, 256, 0, stream>>>(
      z, cell, esm, w1, b1, w2, b2, w3, b3, zc,
      fc1w, fc1b, fc2w, fc2b, fc3w, fc3b, fc4w, W1f, W2f, W3f, fc4wp);
  node_gemm<<<dim3((NNP + 127) / 128, 5), 256, 0, stream>>>(zc, W1f, PQ);
  edge_kernel<<<(NE + 255) / 256, 512, 0, stream>>>(PQ, W2f, W3f, fc4wp, fc4b, ei, out);
}

// Round 4
// 356.799 us; speedup vs baseline: 1.4053x; 1.4053x over previous
//
#include <hip/hip_runtime.h>

// ---------------------------------------------------------------------------
// SLMGAE edge scorer, round 7.
//   P = zc @ fc1_w[0:400] + b1,  Q = zc @ fc1_w[400:800]   (per node)
//   per edge: h1 = relu(P[s]+Q[d]); h2 = relu(h1@W2+b2); h3 = relu(h2@W3+b3);
//   out = h3@w4 + b4
// Round-7 changes vs round 6 (R6 REGRESSED: __launch_bounds__(512,4) forced
// VGPR 64 -> h1i spilled -> WRITE_SIZE 52->236 MB, 335 us. Compiler VGPR cap
// behaves as 256/min_waves_per_EU: (256,2)->128 is the no-spill config):
//   * edge_kernel back to 256 threads, __launch_bounds__(256,2) (R4-proven:
//     92 VGPR, WRITE_SIZE 1.95 MB).
//   * ENTIRE pipeline bf16 -> fp16: gather's unpack/add/relu/repack (~30 VALU
//     per 8 elems) becomes 4x v_pk_add_f16 + 4x v_pk_max_f16 (~3x fewer);
//     packs use v_cvt_pkrtz_f16_f32. fp16 also has MORE mantissa than bf16
//     -> absmax improves. MFMAs -> _f16 variants (same fragment layouts).
//   * fc3 k-blocks 14 -> 13 kept (kb3=13 is all-zero weight).
// ---------------------------------------------------------------------------

using u16    = unsigned short;
using f16    = _Float16;
using f16x8  = __attribute__((ext_vector_type(8))) f16;     // 8 fp16 (4 VGPR)
using f32x4  = __attribute__((ext_vector_type(4))) float;
using f32x16 = __attribute__((ext_vector_type(16))) float;
using i32x4  = __attribute__((ext_vector_type(4))) int;

#define NN   20000   // nodes
#define NNP  20032   // nodes padded (multiple of 64)
#define KD   416     // 400 padded to multiple of 32 (col 400 = bias-one)
#define NE   500000  // edges

// fragment-order element counts
#define W1F_ELEMS (50*13*512)    // 50 n-tiles(16) x 13 kb(32) x 64 lanes x 8
#define W2F_ELEMS (7*26*512)     // 7 n-tiles(32) x 26 kb(16) x 64 x 8
#define W3F_ELEMS (4*14*512)     // 4 n-tiles(32) x 14 kb(16) x 64 x 8
#define F4_ELEMS  128
#define PREP_TOT  (W1F_ELEMS + W2F_ELEMS + W3F_ELEMS + F4_ELEMS)

#define ZC_BLOCKS   (NNP / 4)                    // 5008
#define PREP_BLOCKS ((PREP_TOT + 255) / 256)     // 1777

__device__ __forceinline__ u16 f2h(float f) {               // RNE f32->f16
  f16 h = (f16)f;
  return __builtin_bit_cast(u16, h);
}

// pack two f32 -> packed f16 pair (lo in [15:0]), single HW instr (RTZ)
__device__ __forceinline__ int cvt_pk_f16(float lo, float hi) {
  int r;
  asm("v_cvt_pkrtz_f16_f32 %0, %1, %2" : "=v"(r) : "v"(lo), "v"(hi));
  return r;
}

// packed fp16: relu(p + q) on both halves (2 instrs for 2 elements)
__device__ __forceinline__ int pk_addrelu(int p, int q) {
  int r;
  asm("v_pk_add_f16 %0, %1, %2\n\t"
      "v_pk_max_f16 %0, %0, 0"
      : "=&v"(r) : "v"(p), "v"(q));
  return r;
}

// async global->LDS 16B: lane l's 16B land at ldsbase + l*16 (linear order)
__device__ __forceinline__ void gl_lds16(const u16* g, u16* l) {
  __builtin_amdgcn_global_load_lds(
      (const __attribute__((address_space(1))) unsigned int*)g,
      (__attribute__((address_space(3))) unsigned int*)l, 16, 0, 0);
}

// ---------------------------------------------------------------------------
// K0 (fused): block role by blockIdx.x
//   [0, ZC_BLOCKS)                : build_zc — per-node tiny MLP + zc_f16 rows
//   [ZC_BLOCKS, ZC_BLOCKS+PREP)   : prep_w  — weight transpose/pad/f16, FRAG
//
// prep_w fragment orders (identical lane maps to the bf16 version — MFMA
// fragment layout is dtype-independent on gfx950):
//  W1f[g][kb][l][j] = W1t[n=g*16+(l&15)][k=kb*32+(l>>4)*8+j]   (16x16x32 B-frag)
//  W2f[nt][kb][l][j] = W2t[n=nt*32+(l&31)][k=kb*16+(l>>5)*8+j] (32x32x16 A-frag)
//  W3f[nt][kb][l][j] = W3t[n=nt*32+(l&31)][k=kb*16+(l>>5)*8+j]
// build_zc: zc = [z(64) | m(16) | esm(320) | 1.0 at k=400 | zeros]
// ---------------------------------------------------------------------------
__global__ __launch_bounds__(256) void prep_fused(
    const float* __restrict__ z, const float* __restrict__ cell,
    const float* __restrict__ esm,
    const float* __restrict__ w1, const float* __restrict__ b1,
    const float* __restrict__ w2, const float* __restrict__ b2,
    const float* __restrict__ w3, const float* __restrict__ b3,
    u16* __restrict__ zc,
    const float* __restrict__ fc1, const float* __restrict__ fc1b,
    const float* __restrict__ fc2, const float* __restrict__ fc2b,
    const float* __restrict__ fc3, const float* __restrict__ fc3b,
    const float* __restrict__ fc4,
    u16* __restrict__ W1f, u16* __restrict__ W2f, u16* __restrict__ W3f,
    float* __restrict__ fc4wp)
{
  __shared__ float h1s[4][64];
  __shared__ float h2s[4][32];
  __shared__ float ms[4][16];

  if (blockIdx.x < ZC_BLOCKS) {
    // ------------------------- build_zc ------------------------------------
    int tid = threadIdx.x, g = tid >> 6, t = tid & 63;
    int i = blockIdx.x * 4 + g;
    bool real = (i < NN);
    float c0 = 0, c1 = 0, c2 = 0, c3 = 0;
    if (real) {
      c0 = cell[(size_t)i * 4 + 0]; c1 = cell[(size_t)i * 4 + 1];
      c2 = cell[(size_t)i * 4 + 2]; c3 = cell[(size_t)i * 4 + 3];
    }
    float h = b1[t] + c0 * w1[t] + c1 * w1[64 + t] + c2 * w1[128 + t] + c3 * w1[192 + t];
    h1s[g][t] = fmaxf(h, 0.f);
    __syncthreads();
    if (t < 32) {
      float acc = b2[t];
      #pragma unroll 8
      for (int j = 0; j < 64; j++) acc += h1s[g][j] * w2[j * 32 + t];
      h2s[g][t] = fmaxf(acc, 0.f);
    }
    __syncthreads();
    if (t < 16) {
      float acc = b3[t];
      #pragma unroll 8
      for (int j = 0; j < 32; j++) acc += h2s[g][j] * w3[j * 16 + t];
      ms[g][t] = acc;
    }
    __syncthreads();
    u16* row = zc + (size_t)i * KD;
    for (int k = t; k < KD; k += 64) {
      float v = 0.f;
      if (real) {
        if (k < 64)       v = z[(size_t)i * 64 + k];
        else if (k < 80)  v = ms[g][k - 64];
        else if (k < 400) v = esm[(size_t)i * 320 + (k - 80)];
        else if (k == 400) v = 1.0f;   // bias-one column (fc1b lives in W1f)
      }
      row[k] = f2h(v);
    }
    return;
  }

  // --------------------------- prep_w --------------------------------------
  int idx = (blockIdx.x - ZC_BLOCKS) * 256 + threadIdx.x;
  if (idx < W1F_ELEMS) {
    int j = idx & 7, l = (idx >> 3) & 63, t = idx >> 9;
    int kb = t % 13, g = t / 13;
    int n = g * 16 + (l & 15);
    int k = kb * 32 + (l >> 4) * 8 + j;
    float v = 0.f;
    if (k < 400) v = (n < 400) ? fc1[(size_t)k * 400 + n]
                               : fc1[(size_t)(400 + k) * 400 + (n - 400)];
    else if (k == 400 && n < 400) v = fc1b[n];
    W1f[idx] = f2h(v);
  } else if (idx < W1F_ELEMS + W2F_ELEMS) {
    int r = idx - W1F_ELEMS;
    int j = r & 7, l = (r >> 3) & 63, t = r >> 9;
    int kb = t % 26, nt = t / 26;
    int n = nt * 32 + (l & 31);
    int k = kb * 16 + (l >> 5) * 8 + j;
    float v = 0.f;
    if (n < 200) {
      if (k < 400) v = fc2[(size_t)k * 200 + n];
      else if (k == 400) v = fc2b[n];
    }
    W2f[r] = f2h(v);
  } else if (idx < W1F_ELEMS + W2F_ELEMS + W3F_ELEMS) {
    int r = idx - (W1F_ELEMS + W2F_ELEMS);
    int j = r & 7, l = (r >> 3) & 63, t = r >> 9;
    int kb = t % 14, nt = t / 14;
    int n = nt * 32 + (l & 31);
    int k = kb * 16 + (l >> 5) * 8 + j;
    float v = 0.f;
    if (n < 100) {
      if (k < 200) v = fc3[(size_t)k * 100 + n];
      else if (k == 200) v = fc3b[n];
    }
    W3f[r] = f2h(v);
  } else if (idx < PREP_TOT) {
    int r = idx - (W1F_ELEMS + W2F_ELEMS + W3F_ELEMS);
    fc4wp[r] = (r < 100) ? fc4[r] : 0.f;
  }
}

// ---------------------------------------------------------------------------
// K2: PQ[NNP][800] = zc_f16 @ W1^T (bias via k=400 col), f16 out.
// Dual 16-row A-tiles per wave; B streamed from frag-ordered W1f (coalesced).
// grid (157, 5): 785 blocks (~3 blocks/CU).  B slab per y = 133 KB, L2-hot.
// ---------------------------------------------------------------------------
__global__ __launch_bounds__(256) void node_gemm(
    const u16* __restrict__ zc, const u16* __restrict__ W1f,
    u16* __restrict__ PQ)
{
  int tid = threadIdx.x, w = tid >> 6, l = tid & 63, lm = l & 15, quad = l >> 4;
  int mbase = blockIdx.x * 128 + w * 32;

  int ra = mbase + lm;       if (ra > NNP - 1) ra = NNP - 1;
  int rb = mbase + 16 + lm;  if (rb > NNP - 1) rb = NNP - 1;
  f16x8 a0[13], a1[13];
  const u16* arow0 = zc + (size_t)ra * KD + quad * 8;
  const u16* arow1 = zc + (size_t)rb * KD + quad * 8;
  #pragma unroll
  for (int kb = 0; kb < 13; kb++) {
    a0[kb] = *(const f16x8*)(arow0 + kb * 32);
    a1[kb] = *(const f16x8*)(arow1 + kb * 32);
  }

  for (int nt = 0; nt < 10; nt++) {
    int g = blockIdx.y * 10 + nt;          // global 16-col tile of the 800
    int ncol = g * 16 + lm;
    const u16* bbase = W1f + ((size_t)g * 13 * 64 + l) * 8;
    f32x4 acc0 = {0.f, 0.f, 0.f, 0.f};
    f32x4 acc1 = {0.f, 0.f, 0.f, 0.f};
    #pragma unroll
    for (int kb = 0; kb < 13; kb++) {
      f16x8 b = *(const f16x8*)(bbase + (size_t)kb * 512);
      acc0 = __builtin_amdgcn_mfma_f32_16x16x32_f16(a0[kb], b, acc0, 0, 0, 0);
      acc1 = __builtin_amdgcn_mfma_f32_16x16x32_f16(a1[kb], b, acc1, 0, 0, 0);
    }
    #pragma unroll
    for (int r = 0; r < 4; r++) {
      int row0 = mbase + quad * 4 + r;
      int row1 = row0 + 16;
      if (row0 < NNP) PQ[(size_t)row0 * 800 + ncol] = f2h(acc0[r]);
      if (row1 < NNP) PQ[(size_t)row1 * 800 + ncol] = f2h(acc1[r]);
    }
  }
}

// ---------------------------------------------------------------------------
// K3: edge kernel — 32 edges/wave, mfma 32x32x16_f16, weights double-buffered
// in LDS via async global_load_lds.  Per-tile schedule:
//   issue stage(t+1 -> buf^1)  ||  ds_read+MFMA tile t from buf  ->  sync
// 256 threads, __launch_bounds__(256,2): no-spill config (R4-proven).
// ---------------------------------------------------------------------------
__global__ __launch_bounds__(256, 2) void edge_kernel(
    const u16* __restrict__ PQ, const u16* __restrict__ W2f,
    const u16* __restrict__ W3f, const float* __restrict__ fc4wp,
    const float* __restrict__ fc4b,
    const int* __restrict__ ei, float* __restrict__ out)
{
  __shared__ __align__(16) u16 wsm[2][26 * 512];   // 2 x 26.6 KB = 53.2 KB

  int tid = threadIdx.x, w = tid >> 6, l = tid & 63;
  int c = l & 31, h = l >> 5;
  int e = blockIdx.x * 128 + w * 32 + c;
  int ec = e < NE ? e : NE - 1;
  int s = ei[ec], d = ei[NE + ec];
  const u16* prow = PQ + (size_t)s * 800 + h * 8;        // P (pre-biased)
  const u16* qrow = PQ + (size_t)d * 800 + 400 + h * 8;  // Q

  // issue fc2 tile-0 stage immediately: L2 latency hides under the gather
  for (int kb = w; kb < 26; kb += 4)
    gl_lds16(W2f + ((size_t)kb * 64 + l) * 8, &wsm[0][kb * 512]);

  // ---- gather -> h1 B-frags (kb 0..24 real; kb 25 = bias-one) -------------
  // packed fp16: relu(P+Q) = 1x v_pk_add_f16 + 1x v_pk_max_f16 per 2 elems
  i32x4 h1i[25];
  #pragma unroll
  for (int kb = 0; kb < 25; kb++) {
    i32x4 pv = *(const i32x4*)(prow + kb * 16);
    i32x4 qv = *(const i32x4*)(qrow + kb * 16);
    i32x4 r;
    #pragma unroll
    for (int j2 = 0; j2 < 4; j2++) r[j2] = pk_addrelu(pv[j2], qv[j2]);
    h1i[kb] = r;
  }
  i32x4 bias1 = {0, 0, 0, 0};
  if (h == 0) bias1[0] = 0x3C00;   // h1[k=400] = 1.0 (f16) for every edge

  __syncthreads();                 // drains vmcnt -> buf0 staged for all waves

  // ---- fc2: 7 ntiles of 32 neurons; dbuf-staged weights; h2 packed --------
  int p2[7][8];
  #pragma unroll
  for (int nt = 0; nt < 7; nt++) {
    int cur = nt & 1;
    if (nt < 6) {                               // prefetch next fc2 tile
      for (int kb = w; kb < 26; kb += 4)
        gl_lds16(W2f + (((size_t)(nt + 1) * 26 + kb) * 64 + l) * 8,
                 &wsm[cur ^ 1][kb * 512]);
    } else {                                    // prefetch fc3 tile 0 (13 kb)
      for (int kb = w; kb < 13; kb += 4)
        gl_lds16(W3f + ((size_t)kb * 64 + l) * 8, &wsm[cur ^ 1][kb * 512]);
    }
    f32x16 acc = {0.f,0.f,0.f,0.f,0.f,0.f,0.f,0.f,0.f,0.f,0.f,0.f,0.f,0.f,0.f,0.f};
    __builtin_amdgcn_s_setprio(1);
    #pragma unroll
    for (int kb = 0; kb < 25; kb++) {
      f16x8 a = *(const f16x8*)&wsm[cur][kb * 512 + l * 8];
      acc = __builtin_amdgcn_mfma_f32_32x32x16_f16(
          a, __builtin_bit_cast(f16x8, h1i[kb]), acc, 0, 0, 0);
    }
    {  // kb = 25: bias column k=400
      f16x8 a = *(const f16x8*)&wsm[cur][25 * 512 + l * 8];
      acc = __builtin_amdgcn_mfma_f32_32x32x16_f16(
          a, __builtin_bit_cast(f16x8, bias1), acc, 0, 0, 0);
    }
    __builtin_amdgcn_s_setprio(0);
    #pragma unroll
    for (int q = 0; q < 8; q++)    // relu + pack regs (2q, 2q+1)
      p2[nt][q] = cvt_pk_f16(fmaxf(acc[2 * q], 0.f), fmaxf(acc[2 * q + 1], 0.f));
    __syncthreads();               // next buf staged AND cur free for reuse
  }

  // ---- transpose: C-layout h2 -> fc3 B-frags via shfl_xor(32) -------------
  // only 13 k-blocks needed: k2 = 208..223 (kb3=13) is all-zero weight
  i32x4 b2f[13];
  #pragma unroll
  for (int kb3 = 0; kb3 < 13; kb3++) {
    int nt = kb3 >> 1;
    i32x4 f;
    #pragma unroll
    for (int jj = 0; jj < 4; jj++) {
      int q0 = (jj & 1) + 4 * (kb3 & 1);
      if (jj < 2) {        // source lives in lower half (h_s = 0)
        int x = __shfl_xor(p2[nt][q0 + 2], 32);
        f[jj] = h ? x : p2[nt][q0];
      } else {             // source lives in upper half (h_s = 1)
        int y = __shfl_xor(p2[nt][q0], 32);
        f[jj] = h ? p2[nt][q0 + 2] : y;
      }
    }
    if (kb3 == 12 && h) f[0] |= 0x3C00;   // h2[k2=200] = 1.0 (fc3 bias-one)
    b2f[kb3] = f;
  }

  // ---- fc3 + fc4 (fc3 tile 0 already staged during fc2 nt=6) --------------
  float osum = 0.f;
  #pragma unroll
  for (int nt3 = 0; nt3 < 4; nt3++) {
    int cur = (7 + nt3) & 1;
    if (nt3 < 3) {                              // prefetch next fc3 tile
      for (int kb = w; kb < 13; kb += 4)
        gl_lds16(W3f + (((size_t)(nt3 + 1) * 14 + kb) * 64 + l) * 8,
                 &wsm[cur ^ 1][kb * 512]);
    }
    f32x16 acc = {0.f,0.f,0.f,0.f,0.f,0.f,0.f,0.f,0.f,0.f,0.f,0.f,0.f,0.f,0.f,0.f};
    __builtin_amdgcn_s_setprio(1);
    #pragma unroll
    for (int kb3 = 0; kb3 < 13; kb3++) {
      f16x8 a = *(const f16x8*)&wsm[cur][kb3 * 512 + l * 8];
      acc = __builtin_amdgcn_mfma_f32_32x32x16_f16(
          a, __builtin_bit_cast(f16x8, b2f[kb3]), acc, 0, 0, 0);
    }
    __builtin_amdgcn_s_setprio(0);
    #pragma unroll
    for (int r = 0; r < 16; r++) {
      int rho = (r & 3) + 8 * (r >> 2) + 4 * h + 32 * nt3;
      osum += fmaxf(acc[r], 0.f) * fc4wp[rho];   // pad rows: 0 * 0
    }
    if (nt3 < 3) __syncthreads();
  }
  osum += __shfl_xor(osum, 32);     // combine the two k-halves of this edge
  if (h == 0 && e < NE) out[e] = osum + fc4b[0];
}

// ---------------------------------------------------------------------------
extern "C" void kernel_launch(void* const* d_in, const int* in_sizes, int n_in,
                              void* d_out, int out_size, void* d_ws, size_t ws_size,
                              hipStream_t stream) {
  (void)in_sizes; (void)n_in; (void)out_size; (void)ws_size;
  const float* z    = (const float*)d_in[0];
  const int*   ei   = (const int*)d_in[1];
  const float* cell = (const float*)d_in[2];
  const float* esm  = (const float*)d_in[3];
  const float* w1   = (const float*)d_in[4];
  const float* b1   = (const float*)d_in[5];
  const float* w2   = (const float*)d_in[6];
  const float* b2   = (const float*)d_in[7];
  const float* w3   = (const float*)d_in[8];
  const float* b3   = (const float*)d_in[9];
  const float* fc1w = (const float*)d_in[10];
  const float* fc1b = (const float*)d_in[11];
  const float* fc2w = (const float*)d_in[12];
  const float* fc2b = (const float*)d_in[13];
  const float* fc3w = (const float*)d_in[14];
  const float* fc3b = (const float*)d_in[15];
  const float* fc4w = (const float*)d_in[16];
  const float* fc4b = (const float*)d_in[17];
  float* out = (float*)d_out;

  // workspace layout (u16 units, all 16B-aligned): ~49.6 MB
  u16* zc  = (u16*)d_ws;                        // NNP*416
  u16* PQ  = zc  + (size_t)NNP * KD;            // NNP*800
  u16* W1f = PQ  + (size_t)NNP * 800;           // 332800
  u16* W2f = W1f + W1F_ELEMS;                   // 93184
  u16* W3f = W2f + W2F_ELEMS;                   // 28672
  float* fc4wp = (float*)(W3f + W3F_ELEMS);     // 128 f32

  prep_fused<<<ZC_BLOCKS + PREP_BLOCKS, 256, 0, stream>>>(
      z, cell, esm, w1, b1, w2, b2, w3, b3, zc,
      fc1w, fc1b, fc2w, fc2b, fc3w, fc3b, fc4w, W1f, W2f, W3f, fc4wp);
  node_gemm<<<dim3((NNP + 127) / 128, 5), 256, 0, stream>>>(zc, W1f, PQ);
  edge_kernel<<<(NE + 127) / 128, 256, 0, stream>>>(PQ, W2f, W3f, fc4wp, fc4b, ei, out);
}